// Round 1
// baseline (214.180 us; speedup 1.0000x reference)
//
#include <hip/hip_runtime.h>

#define NN 2048
#define NE 8192
#define ED 10
#define EH 32
#define HID 160
#define KT 5440          // 160 * 34 : k = i*34 + q, q in [0,32)=w2, 32=b2, 33=root
#define KS 10            // split-K factor: 10 chunks of 544 (17 mfma steps)

typedef __attribute__((ext_vector_type(8))) short short8;
typedef __attribute__((ext_vector_type(4))) float f32x4;
typedef unsigned int u32;

__device__ __forceinline__ ushort f2bf(float v) {   // RNE
    u32 u = __float_as_uint(v);
    u += 0x7FFF + ((u >> 16) & 1);
    return (ushort)(u >> 16);
}
__device__ __forceinline__ float bf2f(ushort u) {
    return __uint_as_float(((u32)u) << 16);
}
__device__ __forceinline__ void gl2lds16(const ushort* g, ushort* l) {
    __builtin_amdgcn_global_load_lds(
        (const __attribute__((address_space(1))) u32*)g,
        (__attribute__((address_space(3))) u32*)l, 16, 0, 0);
}

// ================= single prep dispatch: all input-derived work =================
// blocks [0,512): edge MLP (2 sets); [512,552): WcatT build (2 sets x 20 i-panels);
// [552,872): x->bf16; 872: CSR build (single block)
__global__ __launch_bounds__(256) void k_prep(
        const float* __restrict__ x, ushort* __restrict__ xb,
        const float* __restrict__ ea,
        const float* __restrict__ w1a, const float* __restrict__ b1a,
        const float* __restrict__ w1b, const float* __restrict__ b1b,
        float* __restrict__ ha, float* __restrict__ hb,
        const float* __restrict__ w2a, const float* __restrict__ b2a,
        const float* __restrict__ roota,
        const float* __restrict__ w2b, const float* __restrict__ b2b,
        const float* __restrict__ rootb,
        ushort* __restrict__ WcA, ushort* __restrict__ WcB,
        const int* __restrict__ ei, int* __restrict__ doff,
        int* __restrict__ degg, float* __restrict__ dinv,
        int* __restrict__ delist) {
    __shared__ char smem[20608];
    int b = blockIdx.x, t = threadIdx.x;

    if (b < 512) {                       // ---- h = relu(ea@w1+b1), 4 elems/thread
        int set = b >> 8, rel = b & 255;
        const float* w1 = set ? w1b : w1a;
        const float* b1 = set ? b1b : b1a;
        float* h = set ? hb : ha;
        int idx = rel * 1024 + t * 4;
        int e = idx >> 5, j0 = idx & 31;
        float o4[4];
#pragma unroll
        for (int u = 0; u < 4; ++u) {
            float acc = b1[j0 + u];
#pragma unroll
            for (int i = 0; i < ED; ++i) acc += ea[e * ED + i] * w1[i * EH + j0 + u];
            o4[u] = fmaxf(acc, 0.f);
        }
        *(float4*)&h[idx] = *(const float4*)o4;
        return;
    }
    if (b < 552) {                       // ---- WcatT[o][i*34+q] bf16, 8 i's per block
        int rel = b - 512;               // 0..39
        int set = rel / 20, i0 = (rel % 20) * 8;
        const float* w2 = set ? w2b : w2a;
        const float* b2 = set ? b2b : b2a;
        const float* root = set ? rootb : roota;
        ushort* W = set ? WcB : WcA;
        if (t < HID) {
#pragma unroll
            for (int di = 0; di < 8; ++di) {
                int i = i0 + di;
                u32 wv[17];
#pragma unroll
                for (int p = 0; p < 16; ++p) {
                    float v0 = w2[(size_t)(2 * p) * 25600 + i * HID + t];
                    float v1 = w2[(size_t)(2 * p + 1) * 25600 + i * HID + t];
                    wv[p] = ((u32)f2bf(v1) << 16) | f2bf(v0);
                }
                wv[16] = ((u32)f2bf(root[i * HID + t]) << 16) | f2bf(b2[i * HID + t]);
#pragma unroll
                for (int p = 0; p < 17; ++p)
                    *(u32*)&W[(size_t)t * KT + i * 34 + 2 * p] = wv[p];
            }
        }
        return;
    }
    if (b < 872) {                       // ---- x -> bf16, 4 elems/thread
        int idx = (b - 552) * 1024 + t * 4;
        float4 xv = *(const float4*)&x[idx];
        ushort o4[4] = {f2bf(xv.x), f2bf(xv.y), f2bf(xv.z), f2bf(xv.w)};
        *(u32*)&xb[idx] = *(const u32*)&o4[0];
        *(u32*)&xb[idx + 2] = *(const u32*)&o4[2];
        return;
    }
    // ---- CSR build over dst (single block, 256 threads)
    int* deg = (int*)smem;               // NN
    int* cur = deg + NN;                 // NN
    int* part = cur + NN;                // 256
    for (int i = t; i < NN; i += 256) deg[i] = 0;
    __syncthreads();
    for (int e = t; e < NE; e += 256) atomicAdd(&deg[ei[NE + e]], 1);
    __syncthreads();
    int loc[8], s = 0;
#pragma unroll
    for (int i = 0; i < 8; ++i) { loc[i] = s; s += deg[t * 8 + i]; }
    part[t] = s;
    __syncthreads();
    int tot = s;
    for (int st = 1; st < 256; st <<= 1) {
        int v = (t >= st) ? part[t - st] : 0;
        __syncthreads();
        part[t] += v;
        __syncthreads();
    }
    int base = part[t] - tot;
#pragma unroll
    for (int i = 0; i < 8; ++i) {
        int d = t * 8 + i;
        doff[d] = base + loc[i];
        cur[d] = base + loc[i];
        degg[d] = deg[d];
        dinv[d] = 1.0f / fmaxf((float)deg[d], 1.0f);
    }
    __syncthreads();
    for (int e = t; e < NE; e += 256) {
        int d = ei[NE + e];
        int p = atomicAdd(&cur[d], 1);
        delist[p] = e;
    }
}

// ====== scatter: T[d][i*34+q] = dinv * sum_{e->d} h[e][q]*x[src_e][i]  (bf16) ======
// q=32 lane: dinv * sum x[src][i]  (b2 coefficient); q=33 lane: x[d][i] (root).
__global__ __launch_bounds__(160) void k_scatter(
        const ushort* __restrict__ xb, const float* __restrict__ h,
        const int* __restrict__ ei, const int* __restrict__ doff,
        const int* __restrict__ degg, const float* __restrict__ dinv,
        const int* __restrict__ delist, ushort* __restrict__ T) {
    __shared__ float hbuf[32 * EH];
    __shared__ int ebuf[32], sbuf[32];
    int d = blockIdx.x, t = threadIdx.x;
    int o0 = doff[d], dg = degg[d];
    float acc[33];
#pragma unroll
    for (int q = 0; q < 33; ++q) acc[q] = 0.f;
    for (int c0 = 0; c0 < dg; c0 += 32) {
        int nc = min(32, dg - c0);
        __syncthreads();                 // protect ebuf/hbuf reuse across chunks
        if (t < 32 && c0 + t < dg) {
            int e = delist[o0 + c0 + t];
            ebuf[t] = e;
            sbuf[t] = ei[e];             // src
        }
        __syncthreads();
        for (int i = t; i < nc * EH; i += 160)
            hbuf[i] = h[(size_t)ebuf[i >> 5] * EH + (i & 31)];
        __syncthreads();
        for (int j = 0; j < nc; ++j) {
            float xs = bf2f(xb[(size_t)sbuf[j] * HID + t]);
            const float* hj = &hbuf[j * EH];
#pragma unroll
            for (int q = 0; q < 32; ++q) acc[q] += hj[q] * xs;
            acc[32] += xs;
        }
    }
    float di = dinv[d];
    ushort* Trow = T + (size_t)d * KT + t * 34;
    u32 w[17];
#pragma unroll
    for (int p = 0; p < 16; ++p)
        w[p] = ((u32)f2bf(acc[2 * p + 1] * di) << 16) | f2bf(acc[2 * p] * di);
    w[16] = ((u32)xb[(size_t)d * HID + t] << 16) | f2bf(acc[32] * di);
#pragma unroll
    for (int p = 0; p < 17; ++p) *(u32*)&Trow[p * 2] = w[p];
}

// ====== split-K GEMM: Cp[ks] += T[2048,544@ks] @ WcatT^T -> [2048,160] f32 ======
__global__ __launch_bounds__(256) void k_out(const ushort* __restrict__ A,
                                             const ushort* __restrict__ B,
                                             float* __restrict__ Cp) {
    __shared__ ushort sA[128 * 32], sB[160 * 32];
    int tid = threadIdx.x;
    int bm = blockIdx.x * 128;
    int ks = blockIdx.y;
    int k0base = ks * (KT / KS);
    int wid = tid >> 6, lane = tid & 63;
    int wm = (wid >> 1) * 64, wn = (wid & 1) * 80;
    int lr = lane & 15, lk = lane >> 4;
    f32x4 acc[4][5];
#pragma unroll
    for (int i = 0; i < 4; ++i)
#pragma unroll
        for (int j = 0; j < 5; ++j) acc[i][j] = (f32x4){0.f, 0.f, 0.f, 0.f};

    for (int c = 0; c < 17; ++c) {
        int k0 = k0base + c * 32;
#pragma unroll
        for (int i = 0; i < 2; ++i) {     // A tile: 128x32 = 512 x 16B
            int s = tid + i * 256;
            int r = s >> 2, go = (s & 3) * 8;
            gl2lds16(&A[(size_t)(bm + r) * KT + k0 + go], &sA[s * 8]);
        }
#pragma unroll
        for (int i = 0; i < 2; ++i) {     // B tile: 160x32 = 640 x 16B (512 here)
            int s = tid + i * 256;
            int r = s >> 2, go = (s & 3) * 8;
            gl2lds16(&B[(size_t)r * KT + k0 + go], &sB[s * 8]);
        }
        if (tid < 128) {                  // remaining 128 loads: waves 0,1 fully active
            int s = tid + 512;
            int r = s >> 2, go = (s & 3) * 8;
            gl2lds16(&B[(size_t)r * KT + k0 + go], &sB[s * 8]);
        }
        __syncthreads();
        short8 av[4], bv[5];
#pragma unroll
        for (int mt = 0; mt < 4; ++mt)
            av[mt] = *(const short8*)&sA[(wm + mt * 16 + lr) * 32 + lk * 8];
#pragma unroll
        for (int nt = 0; nt < 5; ++nt)
            bv[nt] = *(const short8*)&sB[(wn + nt * 16 + lr) * 32 + lk * 8];
#pragma unroll
        for (int mt = 0; mt < 4; ++mt)
#pragma unroll
            for (int nt = 0; nt < 5; ++nt)
                acc[mt][nt] = __builtin_amdgcn_mfma_f32_16x16x32_bf16(av[mt], bv[nt], acc[mt][nt], 0, 0, 0);
        __syncthreads();
    }
    float* Cb = Cp + (size_t)ks * NN * HID;
#pragma unroll
    for (int mt = 0; mt < 4; ++mt)
#pragma unroll
        for (int nt = 0; nt < 5; ++nt) {
            int m0 = bm + wm + mt * 16 + lk * 4;
            int n = wn + nt * 16 + lr;
#pragma unroll
            for (int r = 0; r < 4; ++r)
                Cb[(size_t)(m0 + r) * HID + n] = acc[mt][nt][r];
        }
}

// ====== reduce split-K partials + bias (+relu+bf16 for layers 0,1) ======
__global__ __launch_bounds__(160) void k_fin(const float* __restrict__ Cp,
        const float* __restrict__ bias, ushort* __restrict__ xn,
        float* __restrict__ out, int last) {
    int d = blockIdx.x, t = threadIdx.x;
    float s = bias[t];
#pragma unroll
    for (int p = 0; p < KS; ++p) s += Cp[(size_t)p * NN * HID + d * HID + t];
    if (last) out[d * HID + t] = s;
    else      xn[d * HID + t] = f2bf(fmaxf(s, 0.f));
}

extern "C" void kernel_launch(void* const* d_in, const int* in_sizes, int n_in,
                              void* d_out, int out_size, void* d_ws, size_t ws_size,
                              hipStream_t stream) {
    const float* x     = (const float*)d_in[0];
    const float* ea    = (const float*)d_in[1];
    const float* w1a   = (const float*)d_in[2];
    const float* b1a   = (const float*)d_in[3];
    const float* w2a   = (const float*)d_in[4];
    const float* b2a   = (const float*)d_in[5];
    const float* roota = (const float*)d_in[6];
    const float* biasa = (const float*)d_in[7];
    const float* w1b   = (const float*)d_in[8];
    const float* b1b   = (const float*)d_in[9];
    const float* w2b   = (const float*)d_in[10];
    const float* b2b   = (const float*)d_in[11];
    const float* rootb = (const float*)d_in[12];
    const float* biasb = (const float*)d_in[13];
    const int*   ei    = (const int*)d_in[14];
    float* out = (float*)d_out;

    char* p = (char*)d_ws;
    ushort* T   = (ushort*)p;  p += (size_t)NN * KT * 2;      // 22.3 MB
    ushort* WcA = (ushort*)p;  p += (size_t)HID * KT * 2;     // 1.74 MB
    ushort* WcB = (ushort*)p;  p += (size_t)HID * KT * 2;
    float* Cp   = (float*)p;   p += (size_t)KS * NN * HID * 4; // 13.1 MB
    float* h_a  = (float*)p;   p += (size_t)NE * EH * 4;
    float* h_b  = (float*)p;   p += (size_t)NE * EH * 4;
    ushort* xb0 = (ushort*)p;  p += (size_t)NN * HID * 2;
    ushort* xn  = (ushort*)p;  p += (size_t)NN * HID * 2;
    int* doff   = (int*)p;     p += NN * 4;
    int* degg   = (int*)p;     p += NN * 4;
    float* dinv = (float*)p;   p += NN * 4;
    int* delist = (int*)p;     p += NE * 4;

    k_prep<<<873, 256, 0, stream>>>(x, xb0, ea, w1a, b1a, w1b, b1b, h_a, h_b,
                                    w2a, b2a, roota, w2b, b2b, rootb, WcA, WcB,
                                    ei, doff, degg, dinv, delist);

    struct Layer { const ushort *xin, *wc; const float *h, *bias; int last; };
    Layer L[3] = {
        {xb0, WcA, h_a, biasa, 0},
        {xn,  WcB, h_b, biasb, 0},
        {xn,  WcB, h_b, biasb, 1},
    };
    for (int l = 0; l < 3; ++l) {
        k_scatter<<<NN, 160, 0, stream>>>(L[l].xin, L[l].h, ei, doff, degg,
                                          dinv, delist, T);
        k_out<<<dim3(NN / 128, KS), 256, 0, stream>>>(T, L[l].wc, Cp);
        k_fin<<<NN, 160, 0, stream>>>(Cp, L[l].bias, xn, out, L[l].last);
    }
}

// Round 3
// 201.140 us; speedup vs baseline: 1.0648x; 1.0648x over previous
//
#include <hip/hip_runtime.h>

#define NN 2048
#define NE 8192
#define ED 10
#define EH 32
#define HID 160
#define KT 5440          // 160 * 34 : k = i*34 + q, q in [0,32)=w2, 32=b2, 33=root
#define KS 10            // split-K: 10 chunks of 544 (17 mfma steps each)
#define KSTEPS 17

typedef __attribute__((ext_vector_type(8))) short short8;
typedef __attribute__((ext_vector_type(4))) float f32x4;
typedef unsigned int u32;

__device__ __forceinline__ ushort f2bf(float v) {   // RNE
    u32 u = __float_as_uint(v);
    u += 0x7FFF + ((u >> 16) & 1);
    return (ushort)(u >> 16);
}
__device__ __forceinline__ float bf2f(ushort u) {
    return __uint_as_float(((u32)u) << 16);
}
__device__ __forceinline__ void gl2lds16(const ushort* g, ushort* l) {
    __builtin_amdgcn_global_load_lds(
        (const __attribute__((address_space(1))) u32*)g,
        (__attribute__((address_space(3))) u32*)l, 16, 0, 0);
}

// ================= single prep dispatch: all input-derived work =================
// blocks [0,512): edge MLP (2 sets); [512,672): WcatT build (2 sets x 80 i-pairs);
// [672,992): x->bf16; 992: CSR build (single block)
__global__ __launch_bounds__(256) void k_prep(
        const float* __restrict__ x, ushort* __restrict__ xb,
        const float* __restrict__ ea,
        const float* __restrict__ w1a, const float* __restrict__ b1a,
        const float* __restrict__ w1b, const float* __restrict__ b1b,
        float* __restrict__ ha, float* __restrict__ hb,
        const float* __restrict__ w2a, const float* __restrict__ b2a,
        const float* __restrict__ roota,
        const float* __restrict__ w2b, const float* __restrict__ b2b,
        const float* __restrict__ rootb,
        ushort* __restrict__ WcA, ushort* __restrict__ WcB,
        const int* __restrict__ ei, int* __restrict__ doff,
        int* __restrict__ degg, float* __restrict__ dinv,
        int* __restrict__ delist) {
    __shared__ __align__(16) char smem[21760];
    int b = blockIdx.x, t = threadIdx.x;

    if (b < 512) {                       // ---- h = relu(ea@w1+b1), 4 elems/thread
        int set = b >> 8, rel = b & 255;
        const float* w1 = set ? w1b : w1a;
        const float* b1 = set ? b1b : b1a;
        float* h = set ? hb : ha;
        int idx = rel * 1024 + t * 4;
        int e = idx >> 5, j0 = idx & 31;
        float o4[4];
#pragma unroll
        for (int u = 0; u < 4; ++u) {
            float acc = b1[j0 + u];
#pragma unroll
            for (int i = 0; i < ED; ++i) acc += ea[e * ED + i] * w1[i * EH + j0 + u];
            o4[u] = fmaxf(acc, 0.f);
        }
        *(float4*)&h[idx] = *(const float4*)o4;
        return;
    }
    if (b < 672) {                       // ---- WcatT[o][i*34+q] bf16, LDS-coalesced
        int rel = b - 512;               // 0..159
        int set = rel / 80, i0 = (rel % 80) * 2;
        u32 (*tile)[34] = (u32(*)[34])smem;   // [160 o][34 u32] = 21760 B
        const float* w2 = set ? w2b : w2a;
        const float* b2 = set ? b2b : b2a;
        const float* root = set ? rootb : roota;
        ushort* W = set ? WcB : WcA;
        if (t < HID) {
#pragma unroll
            for (int di = 0; di < 2; ++di) {
                int i = i0 + di;
#pragma unroll
                for (int p = 0; p < 16; ++p) {
                    float v0 = w2[(size_t)(2 * p) * 25600 + i * HID + t];
                    float v1 = w2[(size_t)(2 * p + 1) * 25600 + i * HID + t];
                    tile[t][di * 17 + p] = ((u32)f2bf(v1) << 16) | f2bf(v0);
                }
                tile[t][di * 17 + 16] = ((u32)f2bf(root[i * HID + t]) << 16) |
                                        f2bf(b2[i * HID + t]);
            }
        }
        __syncthreads();
        u32* dst = (u32*)W;
        for (int w = t; w < 5440; w += 256) {   // coalesced: 34 consecutive u32/row
            int o = w / 34, j = w - o * 34;
            dst[(size_t)o * 2720 + i0 * 17 + j] = tile[o][j];
        }
        return;
    }
    if (b < 992) {                       // ---- x -> bf16, 4 elems/thread
        int idx = (b - 672) * 1024 + t * 4;
        float4 xv = *(const float4*)&x[idx];
        ushort o4[4] = {f2bf(xv.x), f2bf(xv.y), f2bf(xv.z), f2bf(xv.w)};
        *(u32*)&xb[idx] = *(const u32*)&o4[0];
        *(u32*)&xb[idx + 2] = *(const u32*)&o4[2];
        return;
    }
    // ---- CSR build over dst (single block, 256 threads)
    int* deg = (int*)smem;               // NN
    int* cur = deg + NN;                 // NN
    int* part = cur + NN;                // 256
    for (int i = t; i < NN; i += 256) deg[i] = 0;
    __syncthreads();
    for (int e = t; e < NE; e += 256) atomicAdd(&deg[ei[NE + e]], 1);
    __syncthreads();
    int loc[8], s = 0;
#pragma unroll
    for (int i = 0; i < 8; ++i) { loc[i] = s; s += deg[t * 8 + i]; }
    part[t] = s;
    __syncthreads();
    int tot = s;
    for (int st = 1; st < 256; st <<= 1) {
        int v = (t >= st) ? part[t - st] : 0;
        __syncthreads();
        part[t] += v;
        __syncthreads();
    }
    int base = part[t] - tot;
#pragma unroll
    for (int i = 0; i < 8; ++i) {
        int d = t * 8 + i;
        doff[d] = base + loc[i];
        cur[d] = base + loc[i];
        degg[d] = deg[d];
        dinv[d] = 1.0f / fmaxf((float)deg[d], 1.0f);
    }
    __syncthreads();
    for (int e = t; e < NE; e += 256) {
        int d = ei[NE + e];
        int p = atomicAdd(&cur[d], 1);
        delist[p] = e;
    }
}

// ====== scatter: T[d][i*34+q] = dinv * sum_{e->d} h[e][q]*x[src_e][i]  (bf16) ======
// q=32 lane: dinv * sum x[src][i]  (b2 coefficient); q=33 lane: x[d][i] (root).
// Row staged in LDS, written out fully coalesced.
__global__ __launch_bounds__(160) void k_scatter(
        const ushort* __restrict__ xb, const float* __restrict__ h,
        const int* __restrict__ ei, const int* __restrict__ doff,
        const int* __restrict__ degg, const float* __restrict__ dinv,
        const int* __restrict__ delist, ushort* __restrict__ T) {
    __shared__ float hbuf[32 * EH];
    __shared__ int ebuf[32], sbuf[32];
    __shared__ u32 rowbuf[KT / 2];       // 2720 u32 = one T row
    int d = blockIdx.x, t = threadIdx.x;
    int o0 = doff[d], dg = degg[d];
    float acc[33];
#pragma unroll
    for (int q = 0; q < 33; ++q) acc[q] = 0.f;
    for (int c0 = 0; c0 < dg; c0 += 32) {
        int nc = min(32, dg - c0);
        __syncthreads();                 // protect ebuf/hbuf reuse across chunks
        if (t < nc) {
            int e = delist[o0 + c0 + t];
            ebuf[t] = e;
            sbuf[t] = ei[e];             // src
        }
        __syncthreads();
        for (int i = t; i < nc * EH; i += 160)
            hbuf[i] = h[(size_t)ebuf[i >> 5] * EH + (i & 31)];
        __syncthreads();
        for (int j = 0; j < nc; ++j) {
            float xs = bf2f(xb[(size_t)sbuf[j] * HID + t]);
            const float* hj = &hbuf[j * EH];
#pragma unroll
            for (int q = 0; q < 32; ++q) acc[q] += hj[q] * xs;
            acc[32] += xs;
        }
    }
    float di = dinv[d];
#pragma unroll
    for (int p = 0; p < 16; ++p)
        rowbuf[t * 17 + p] = ((u32)f2bf(acc[2 * p + 1] * di) << 16) |
                             f2bf(acc[2 * p] * di);
    rowbuf[t * 17 + 16] = ((u32)xb[(size_t)d * HID + t] << 16) | f2bf(acc[32] * di);
    __syncthreads();
    u32* Trow = (u32*)(T + (size_t)d * KT);
    for (int w = t; w < KT / 2; w += 160) Trow[w] = rowbuf[w];  // 17 coalesced u32/thread
}

// ====== split-K GEMM (double-buffered): Cp[ks] = T[2048,544@ks] @ WcatT^T ======
__global__ __launch_bounds__(256) void k_out(const ushort* __restrict__ A,
                                             const ushort* __restrict__ B,
                                             float* __restrict__ Cp) {
    __shared__ ushort sA[2][128 * 32], sB[2][160 * 32];
    int tid = threadIdx.x;
    int bm = blockIdx.x * 128, ks = blockIdx.y;
    int k0base = ks * (KT / KS);
    int wid = tid >> 6, lane = tid & 63;
    int wm = (wid >> 1) * 64, wn = (wid & 1) * 80;
    int lr = lane & 15, lk = lane >> 4;
    f32x4 acc[4][5];
#pragma unroll
    for (int i = 0; i < 4; ++i)
#pragma unroll
        for (int j = 0; j < 5; ++j) acc[i][j] = (f32x4){0.f, 0.f, 0.f, 0.f};

    auto stage = [&](int buf, int c) {
        int k0 = k0base + c * 32;
#pragma unroll
        for (int i = 0; i < 2; ++i) {     // A tile: 128x32 = 512 x 16B
            int s = tid + i * 256;
            int r = s >> 2, go = (s & 3) * 8;
            gl2lds16(&A[(size_t)(bm + r) * KT + k0 + go], &sA[buf][s * 8]);
        }
#pragma unroll
        for (int i = 0; i < 2; ++i) {     // B tile: 160x32 = 640 x 16B
            int s = tid + i * 256;
            int r = s >> 2, go = (s & 3) * 8;
            gl2lds16(&B[(size_t)r * KT + k0 + go], &sB[buf][s * 8]);
        }
        if (tid < 128) {                  // remaining 128: waves 0,1 fully active
            int s = tid + 512;
            int r = s >> 2, go = (s & 3) * 8;
            gl2lds16(&B[(size_t)r * KT + k0 + go], &sB[buf][s * 8]);
        }
    };
    stage(0, 0);
    __syncthreads();
    for (int c = 0; c < KSTEPS; ++c) {
        int cur = c & 1;
        if (c + 1 < KSTEPS) stage(cur ^ 1, c + 1);  // prefetch hides under MFMA
        short8 av[4], bv[5];
#pragma unroll
        for (int mt = 0; mt < 4; ++mt)
            av[mt] = *(const short8*)&sA[cur][(wm + mt * 16 + lr) * 32 + lk * 8];
#pragma unroll
        for (int nt = 0; nt < 5; ++nt)
            bv[nt] = *(const short8*)&sB[cur][(wn + nt * 16 + lr) * 32 + lk * 8];
#pragma unroll
        for (int mt = 0; mt < 4; ++mt)
#pragma unroll
            for (int nt = 0; nt < 5; ++nt)
                acc[mt][nt] = __builtin_amdgcn_mfma_f32_16x16x32_bf16(
                    av[mt], bv[nt], acc[mt][nt], 0, 0, 0);
        __syncthreads();
    }
    float* Cb = Cp + (size_t)ks * NN * HID;
#pragma unroll
    for (int mt = 0; mt < 4; ++mt)
#pragma unroll
        for (int nt = 0; nt < 5; ++nt) {
            int m0 = bm + wm + mt * 16 + lk * 4;
            int n = wn + nt * 16 + lr;
#pragma unroll
            for (int r = 0; r < 4; ++r)
                Cb[(size_t)(m0 + r) * HID + n] = acc[mt][nt][r];
        }
}

// ====== reduce split-K partials + bias (+relu+bf16 for layers 0,1) ======
__global__ __launch_bounds__(160) void k_fin(const float* __restrict__ Cp,
        const float* __restrict__ bias, ushort* __restrict__ xn,
        float* __restrict__ out, int last) {
    int d = blockIdx.x, t = threadIdx.x;
    float s = bias[t];
#pragma unroll
    for (int p = 0; p < KS; ++p) s += Cp[(size_t)p * NN * HID + d * HID + t];
    if (last) out[d * HID + t] = s;
    else      xn[d * HID + t] = f2bf(fmaxf(s, 0.f));
}

extern "C" void kernel_launch(void* const* d_in, const int* in_sizes, int n_in,
                              void* d_out, int out_size, void* d_ws, size_t ws_size,
                              hipStream_t stream) {
    const float* x     = (const float*)d_in[0];
    const float* ea    = (const float*)d_in[1];
    const float* w1a   = (const float*)d_in[2];
    const float* b1a   = (const float*)d_in[3];
    const float* w2a   = (const float*)d_in[4];
    const float* b2a   = (const float*)d_in[5];
    const float* roota = (const float*)d_in[6];
    const float* biasa = (const float*)d_in[7];
    const float* w1b   = (const float*)d_in[8];
    const float* b1b   = (const float*)d_in[9];
    const float* w2b   = (const float*)d_in[10];
    const float* b2b   = (const float*)d_in[11];
    const float* rootb = (const float*)d_in[12];
    const float* biasb = (const float*)d_in[13];
    const int*   ei    = (const int*)d_in[14];
    float* out = (float*)d_out;

    char* p = (char*)d_ws;
    ushort* T   = (ushort*)p;  p += (size_t)NN * KT * 2;       // 22.3 MB
    ushort* WcA = (ushort*)p;  p += (size_t)HID * KT * 2;      // 1.74 MB
    ushort* WcB = (ushort*)p;  p += (size_t)HID * KT * 2;
    float* Cp   = (float*)p;   p += (size_t)KS * NN * HID * 4; // 13.1 MB
    float* h_a  = (float*)p;   p += (size_t)NE * EH * 4;
    float* h_b  = (float*)p;   p += (size_t)NE * EH * 4;
    ushort* xb0 = (ushort*)p;  p += (size_t)NN * HID * 2;
    ushort* xn  = (ushort*)p;  p += (size_t)NN * HID * 2;
    int* doff   = (int*)p;     p += NN * 4;
    int* degg   = (int*)p;     p += NN * 4;
    float* dinv = (float*)p;   p += NN * 4;
    int* delist = (int*)p;     p += NE * 4;

    k_prep<<<993, 256, 0, stream>>>(x, xb0, ea, w1a, b1a, w1b, b1b, h_a, h_b,
                                    w2a, b2a, roota, w2b, b2b, rootb, WcA, WcB,
                                    ei, doff, degg, dinv, delist);

    struct Layer { const ushort *xin, *wc; const float *h, *bias; int last; };
    Layer L[3] = {
        {xb0, WcA, h_a, biasa, 0},
        {xn,  WcB, h_b, biasb, 0},
        {xn,  WcB, h_b, biasb, 1},
    };
    for (int l = 0; l < 3; ++l) {
        k_scatter<<<NN, 160, 0, stream>>>(L[l].xin, L[l].h, ei, doff, degg,
                                          dinv, delist, T);
        k_out<<<dim3(NN / 128, KS), 256, 0, stream>>>(T, L[l].wc, Cp);
        k_fin<<<NN, 160, 0, stream>>>(Cp, L[l].bias, xn, out, L[l].last);
    }
}